// Round 1
// baseline (75.867 us; speedup 1.0000x reference)
//
#include <hip/hip_runtime.h>
#include <math.h>

// Bit-exact-to-numpy float32 helpers: block fp contraction (HIP defaults to
// -ffp-contract=fast; an fma vs mul+add 1-ulp difference can flip the
// ns=ceil(seg/0.2) quantization or the ld>=0 light-hit decision, which moves
// a pixel by up to ~0.07 — over the 1.84e-2 threshold).
__device__ __forceinline__ float fmulr(float a, float b) { return __fmul_rn(a, b); }
__device__ __forceinline__ float faddr(float a, float b) { return __fadd_rn(a, b); }
__device__ __forceinline__ float fsubr(float a, float b) { return __fsub_rn(a, b); }

struct Col { float x, y, z; };

// One pixel of the ray march. Decision chain (a,b,disc,x1,x2,seg,ns,step,t,
// pc,lb,lc,ld,lsq,vt1) replicates numpy's op order exactly; exp() results only
// feed continuous outputs so fast __expf is fine there.
__device__ __forceinline__ Col shade(float rdx, float rdy, float rdz,
                                     float cx, float cy, float cz,
                                     float rr,               // r*r
                                     float ocx, float ocy, float ocz,
                                     float cc)               // c = oc·oc - r*r
{
    const float BGx = 0.572f, BGy = 0.772f, BGz = 0.921f;
    Col out = {BGx, BGy, BGz};

    // a = sum(rd*rd); b = 2*sum(rd*oc); disc = b*b - (4*a)*c
    float a = faddr(faddr(fmulr(rdx, rdx), fmulr(rdy, rdy)), fmulr(rdz, rdz));
    float b = fmulr(2.0f, faddr(faddr(fmulr(rdx, ocx), fmulr(rdy, ocy)), fmulr(rdz, ocz)));
    float disc = fsubr(fmulr(b, b), fmulr(fmulr(4.0f, a), cc));
    if (disc < 0.0f) return out;                 // hit requires disc >= 0

    float sq = sqrtf(disc > 0.0f ? disc : 1.0f); // where(disc>0, disc, 1)
    float twoa = fmulr(2.0f, a);
    float x2 = faddr(-b, sq) / twoa;             // IEEE div (HIP default correctly rounded)
    if (x2 < 0.0f) return out;                   // hit requires x2 >= 0
    float x1 = fsubr(-b, sq) / twoa;

    float t0 = fmaxf(x1, 0.0f);
    float t1 = x2;
    float seg = fsubr(t1, t0);
    float ns = ceilf(seg / 0.2f);                // exact ceil of IEEE div, matches numpy
    float ns_safe = fmaxf(ns, 1.0f);
    float step = seg / ns_safe;
    int nsi = (int)fminf(ns, 12.0f);             // MAX_STEPS=12; ns >= 0 here

    float acc = 0.0f;
    for (int k = 0; k < nsi; ++k) {
        float kph = (float)k + 0.5f;             // exact
        float t = fsubr(t1, fmulr(kph, step));
        // p = RO + t*rd ; pc = p - center   (RO = (0,0,3))
        float pcx = fsubr(faddr(0.0f, fmulr(t, rdx)), cx);
        float pcy = fsubr(faddr(0.0f, fmulr(t, rdy)), cy);
        float pcz = fsubr(faddr(3.0f, fmulr(t, rdz)), cz);
        float lb = fmulr(2.0f, pcy);
        float lc = fsubr(faddr(faddr(fmulr(pcx, pcx), fmulr(pcy, pcy)), fmulr(pcz, pcz)), rr);
        float ld = fsubr(fmulr(lb, lb), fmulr(4.0f, lc));
        if (ld >= 0.0f) {
            float lsq = sqrtf(ld > 0.0f ? ld : 1.0f);
            float vt1 = fmulr(faddr(-lb, lsq), 0.5f);  // /2 is exact
            if (vt1 >= 0.0f) {
                // la = exp(-1.2 * vt1): continuous contribution, fast exp ok
                acc += __expf(-1.2f * vt1);
            }
        }
    }

    // transparency = s**ns = exp(-0.6*step*ns); s**(ns+1) likewise.
    // Continuous in all inputs -> fast exp, regular arithmetic fine.
    float sn  = __expf(-0.6f * (step * ns));
    float sn1 = __expf(-0.6f * (step * (ns + 1.0f)));
    float result = 0.6f * step * sn1 * acc;      // SCATTERING*DENSITY = 0.6
    out.x = BGx * sn + 1.3f * result;
    out.y = BGy * sn + 0.3f * result;
    out.z = BGz * sn + 0.9f * result;
    return out;
}

__global__ __launch_bounds__(256)
void raymarch_kernel(const float* __restrict__ scene,
                     const float4* __restrict__ dirs4,
                     float4* __restrict__ out4,
                     int npix)
{
    int tid = blockIdx.x * blockDim.x + threadIdx.x;
    int base = tid * 4;
    if (base >= npix) return;

    // Scene params: uniform -> scalar loads, L1/L2 broadcast.
    float cx = scene[0], cy = scene[1], cz = scene[2], r = scene[3];
    float rr = fmulr(r, r);
    float ocx = fsubr(0.0f, cx);                 // oc = RO - center, RO=(0,0,3)
    float ocy = fsubr(0.0f, cy);
    float ocz = fsubr(3.0f, cz);
    float cc = fsubr(faddr(faddr(fmulr(ocx, ocx), fmulr(ocy, ocy)), fmulr(ocz, ocz)), rr);

    if (base + 3 < npix) {
        // 4 pixels = 12 floats = 3 float4s, fully coalesced 16B/lane.
        float4 v0 = dirs4[tid * 3 + 0];
        float4 v1 = dirs4[tid * 3 + 1];
        float4 v2 = dirs4[tid * 3 + 2];

        Col c0 = shade(v0.x, v0.y, v0.z, cx, cy, cz, rr, ocx, ocy, ocz, cc);
        Col c1 = shade(v0.w, v1.x, v1.y, cx, cy, cz, rr, ocx, ocy, ocz, cc);
        Col c2 = shade(v1.z, v1.w, v2.x, cx, cy, cz, rr, ocx, ocy, ocz, cc);
        Col c3 = shade(v2.y, v2.z, v2.w, cx, cy, cz, rr, ocx, ocy, ocz, cc);

        out4[tid * 3 + 0] = make_float4(c0.x, c0.y, c0.z, c1.x);
        out4[tid * 3 + 1] = make_float4(c1.y, c1.z, c2.x, c2.y);
        out4[tid * 3 + 2] = make_float4(c2.z, c3.x, c3.y, c3.z);
    } else {
        // Tail safety (unused for 1024x1024 but keeps the kernel generic).
        const float* dirs = (const float*)dirs4;
        float* out = (float*)out4;
        for (int p = base; p < npix; ++p) {
            Col c = shade(dirs[3 * p + 0], dirs[3 * p + 1], dirs[3 * p + 2],
                          cx, cy, cz, rr, ocx, ocy, ocz, cc);
            out[3 * p + 0] = c.x;
            out[3 * p + 1] = c.y;
            out[3 * p + 2] = c.z;
        }
    }
}

extern "C" void kernel_launch(void* const* d_in, const int* in_sizes, int n_in,
                              void* d_out, int out_size, void* d_ws, size_t ws_size,
                              hipStream_t stream) {
    const float* scene = (const float*)d_in[0];   // [1,4] float32: cx,cy,cz,r
    const float* dirs  = (const float*)d_in[1];   // [1024,1024,3] float32
    float* out = (float*)d_out;                   // [1024,1024,3] float32

    int npix = in_sizes[1] / 3;
    int nthreads = (npix + 3) / 4;
    dim3 block(256);
    dim3 grid((nthreads + 255) / 256);
    raymarch_kernel<<<grid, block, 0, stream>>>(scene, (const float4*)dirs,
                                                (float4*)out, npix);
}

// Round 2
// 71.944 us; speedup vs baseline: 1.0545x; 1.0545x over previous
//
#include <hip/hip_runtime.h>
#include <math.h>

// Bit-exact-to-numpy float32 helpers: block fp contraction (HIP defaults to
// -ffp-contract=fast; an fma vs mul+add 1-ulp difference can flip the
// ns=ceil(seg/0.2) quantization or the ld>=0 / vt1>=0 light-hit decisions,
// which move a pixel by up to ~0.07 — over the 1.84e-2 threshold).
// DECISION CHAIN IS FROZEN: a,b,disc,x1,x2,seg,ns,step,t,pc,lb,lc,ld,lsq,vt1
// replicate the reference op-for-op; only bitwise-identity simplifications
// are allowed (see shade1). __expf feeds continuous outputs only.
__device__ __forceinline__ float fmulr(float a, float b) { return __fmul_rn(a, b); }
__device__ __forceinline__ float faddr(float a, float b) { return __fadd_rn(a, b); }
__device__ __forceinline__ float fsubr(float a, float b) { return __fsub_rn(a, b); }

struct Col { float x, y, z; };

// ---- Specialized path: center=(0,0,0), radius=1 (the actual scene) ----
// Bitwise-identical to the generic path for these parameters:
//   oc = (0,0,3);  b = 2*((rdx*0+rdy*0)+rdz*3) == 2*(rdz*3)   [x+0==x, rdz*3!=0]
//   cc = ((0+0)+9)-1 == 8 exactly;  rr = 1*1 == 1 exactly
//   pcx = (0 + t*rdx) - 0 == t*rdx up to -0/+0, which dies in pcx^2
//   pcy likewise (lb=2*pcy: +-0 difference dies in lb^2 and in -lb+lsq, lsq>0)
//   pcz = (3 + t*rdz) - 0 == 3 + t*rdz
__device__ __forceinline__ Col shade1(float rdx, float rdy, float rdz)
{
    const float BGx = 0.572f, BGy = 0.772f, BGz = 0.921f;
    Col out = {BGx, BGy, BGz};

    float a = faddr(faddr(fmulr(rdx, rdx), fmulr(rdy, rdy)), fmulr(rdz, rdz));
    float b = fmulr(2.0f, fmulr(rdz, 3.0f));
    float disc = fsubr(fmulr(b, b), fmulr(fmulr(4.0f, a), 8.0f));
    if (disc < 0.0f) return out;

    float sq = sqrtf(disc > 0.0f ? disc : 1.0f); // IEEE sqrt, matches np.sqrt
    float twoa = fmulr(2.0f, a);
    float x2 = faddr(-b, sq) / twoa;             // IEEE div
    if (x2 < 0.0f) return out;
    float x1 = fsubr(-b, sq) / twoa;

    float t0 = fmaxf(x1, 0.0f);
    float t1 = x2;
    float seg = fsubr(t1, t0);
    float ns = ceilf(seg / 0.2f);                // frozen quantization
    float step = seg / fmaxf(ns, 1.0f);
    int nsi = (int)fminf(ns, 12.0f);

    float acc = 0.0f;
    for (int k = 0; k < nsi; ++k) {
        float t = fsubr(t1, fmulr((float)k + 0.5f, step));
        float pcx = fmulr(t, rdx);
        float pcy = fmulr(t, rdy);
        float pcz = faddr(3.0f, fmulr(t, rdz));
        float lb = fmulr(2.0f, pcy);
        float lc = fsubr(faddr(faddr(fmulr(pcx, pcx), fmulr(pcy, pcy)), fmulr(pcz, pcz)), 1.0f);
        float ld = fsubr(fmulr(lb, lb), fmulr(4.0f, lc));
        if (ld >= 0.0f) {
            float lsq = sqrtf(ld > 0.0f ? ld : 1.0f);
            float vt1 = fmulr(faddr(-lb, lsq), 0.5f);
            if (vt1 >= 0.0f) acc += __expf(-1.2f * vt1);  // continuous only
        }
    }

    float sn  = __expf(-0.6f * (step * ns));          // continuous only
    float sn1 = __expf(-0.6f * (step * (ns + 1.0f)));
    float result = 0.6f * step * sn1 * acc;
    out.x = BGx * sn + 1.3f * result;
    out.y = BGy * sn + 0.3f * result;
    out.z = BGz * sn + 0.9f * result;
    return out;
}

// ---- Generic fallback (any scene), same numerics as round 1 ----
__device__ __forceinline__ Col shadeg(float rdx, float rdy, float rdz,
                                      float cx, float cy, float cz,
                                      float rr, float ocx, float ocy, float ocz,
                                      float cc)
{
    const float BGx = 0.572f, BGy = 0.772f, BGz = 0.921f;
    Col out = {BGx, BGy, BGz};

    float a = faddr(faddr(fmulr(rdx, rdx), fmulr(rdy, rdy)), fmulr(rdz, rdz));
    float b = fmulr(2.0f, faddr(faddr(fmulr(rdx, ocx), fmulr(rdy, ocy)), fmulr(rdz, ocz)));
    float disc = fsubr(fmulr(b, b), fmulr(fmulr(4.0f, a), cc));
    if (disc < 0.0f) return out;

    float sq = sqrtf(disc > 0.0f ? disc : 1.0f);
    float twoa = fmulr(2.0f, a);
    float x2 = faddr(-b, sq) / twoa;
    if (x2 < 0.0f) return out;
    float x1 = fsubr(-b, sq) / twoa;

    float t0 = fmaxf(x1, 0.0f);
    float t1 = x2;
    float seg = fsubr(t1, t0);
    float ns = ceilf(seg / 0.2f);
    float step = seg / fmaxf(ns, 1.0f);
    int nsi = (int)fminf(ns, 12.0f);

    float acc = 0.0f;
    for (int k = 0; k < nsi; ++k) {
        float t = fsubr(t1, fmulr((float)k + 0.5f, step));
        float pcx = fsubr(faddr(0.0f, fmulr(t, rdx)), cx);
        float pcy = fsubr(faddr(0.0f, fmulr(t, rdy)), cy);
        float pcz = fsubr(faddr(3.0f, fmulr(t, rdz)), cz);
        float lb = fmulr(2.0f, pcy);
        float lc = fsubr(faddr(faddr(fmulr(pcx, pcx), fmulr(pcy, pcy)), fmulr(pcz, pcz)), rr);
        float ld = fsubr(fmulr(lb, lb), fmulr(4.0f, lc));
        if (ld >= 0.0f) {
            float lsq = sqrtf(ld > 0.0f ? ld : 1.0f);
            float vt1 = fmulr(faddr(-lb, lsq), 0.5f);
            if (vt1 >= 0.0f) acc += __expf(-1.2f * vt1);
        }
    }

    float sn  = __expf(-0.6f * (step * ns));
    float sn1 = __expf(-0.6f * (step * (ns + 1.0f)));
    float result = 0.6f * step * sn1 * acc;
    out.x = BGx * sn + 1.3f * result;
    out.y = BGy * sn + 0.3f * result;
    out.z = BGz * sn + 0.9f * result;
    return out;
}

// 1 pixel/thread: 16384 waves (vs 4096 in round 1) — latency-bound fix.
__global__ __launch_bounds__(256)
void raymarch_kernel(const float* __restrict__ scene,
                     const float* __restrict__ dirs,
                     float* __restrict__ out,
                     int npix)
{
    int p = blockIdx.x * blockDim.x + threadIdx.x;
    if (p >= npix) return;

    float rdx = dirs[3 * p + 0];
    float rdy = dirs[3 * p + 1];
    float rdz = dirs[3 * p + 2];

    // Uniform scalar loads + uniform branch (s_cbranch, no divergence).
    float cx = scene[0], cy = scene[1], cz = scene[2], r = scene[3];

    Col c;
    if (cx == 0.0f && cy == 0.0f && cz == 0.0f && r == 1.0f) {
        c = shade1(rdx, rdy, rdz);
    } else {
        float rr = fmulr(r, r);
        float ocx = fsubr(0.0f, cx);
        float ocy = fsubr(0.0f, cy);
        float ocz = fsubr(3.0f, cz);
        float cc = fsubr(faddr(faddr(fmulr(ocx, ocx), fmulr(ocy, ocy)), fmulr(ocz, ocz)), rr);
        c = shadeg(rdx, rdy, rdz, cx, cy, cz, rr, ocx, ocy, ocz, cc);
    }

    out[3 * p + 0] = c.x;
    out[3 * p + 1] = c.y;
    out[3 * p + 2] = c.z;
}

extern "C" void kernel_launch(void* const* d_in, const int* in_sizes, int n_in,
                              void* d_out, int out_size, void* d_ws, size_t ws_size,
                              hipStream_t stream) {
    const float* scene = (const float*)d_in[0];   // [1,4]: cx,cy,cz,r
    const float* dirs  = (const float*)d_in[1];   // [1024,1024,3] float32
    float* out = (float*)d_out;                   // [1024,1024,3] float32

    int npix = in_sizes[1] / 3;
    dim3 block(256);
    dim3 grid((npix + 255) / 256);
    raymarch_kernel<<<grid, block, 0, stream>>>(scene, dirs, out, npix);
}